// Round 4
// baseline (193.319 us; speedup 1.0000x reference)
//
#include <hip/hip_runtime.h>
#include <stdint.h>

// ---------------------------------------------------------------------------
// d128snn_delays, round 14 = R13 + counted-wait dbuf-B pipeline in gemm_rk64
// (80KB LDS exact, 2 blk/CU kept) + fir last-tile poison-row masking.
// Measured-dead-end ledger:
//   - inline BN in GEMM staging (R6): +VALU in K-loop critical path, net -.
//   - cooperative mega-kernel (R9): grid.sync() ~110us each on gfx950 -> 5x.
//   - XCD-aware swizzle (R10): serializes A-fill through one XCD's L2. -10us.
//   - R12 device-scope semaphore BN fusion: +55us PER SYNC (fir 77us,
//     MfmaUtil 1.5%, 95% spin). ANY grid-wide sync on gfx950 ~ +55us. Never.
// R13 (dbuf fir + vec setup): 198.7 -> 188.8us, matched prediction.
// Budget: ~42us harness fill + ~77us kernels + ~45us dispatch gaps.
// ---------------------------------------------------------------------------

#define T_LEN 100
#define B_SZ  128
#define M_ROWS 12800
#define R_RANK 4
#define K_FIR 448

typedef __bf16 v8bf __attribute__((ext_vector_type(8)));
typedef float  v4f  __attribute__((ext_vector_type(4)));
typedef unsigned int uint32;
typedef unsigned short ushort_t;

// PHI[tau][r] = exp(-u^2/2) * T_r(u), u = (tau-12)/12  (Chebyshev basis)
struct PhiT { float v[25][R_RANK]; };
constexpr double cexp_(double x) {
  double s = 1.0, t = 1.0;
  for (int n = 1; n < 30; ++n) { t = t * x / n; s += t; }
  return s;
}
constexpr PhiT make_phi() {
  PhiT P{};
  for (int tau = 0; tau < 25; ++tau) {
    double u = (tau - 12) / 12.0;
    double g = cexp_(-0.5 * u * u);
    double T0 = 1.0, T1 = u;
    P.v[tau][0] = (float)(g * T0);
    P.v[tau][1] = (float)(g * T1);
    for (int r = 2; r < R_RANK; ++r) {
      double T2 = 2.0 * u * T1 - T0;
      P.v[tau][r] = (float)(g * T2);
      T0 = T1; T1 = T2;
    }
  }
  return P;
}
constexpr PhiT PHI = make_phi();

__device__ __forceinline__ void gl_lds16(const void* g, void* l) {
  __builtin_amdgcn_global_load_lds(
      (const __attribute__((address_space(1))) char*)g,
      (__attribute__((address_space(3))) char*)l, 16, 0, 0);
}

// ---------------------------------------------------------------------------
// Fused setup: 3x build_wr (Chebyshev/Bessel coeffs) + build_afir + fill_xb
// (vectorized: float4 loads, 8B bf16x4 stores) + stats zero.
// ---------------------------------------------------------------------------
__device__ __forceinline__ void build_wr_body(
    const float* __restrict__ W, const float* __restrict__ P,
    __bf16* __restrict__ Wr, int CIN, int CINP, int COUT, int COUTP, int o) {
  for (int i = threadIdx.x; i < CINP; i += blockDim.x) {
    bool valid = (o < COUT) && (i < CIN);
    float w = valid ? W[(size_t)o * CIN + i] : 0.f;
    float p = valid ? P[(size_t)o * CIN + i] : 0.f;
    float S = 0.f;
#pragma unroll
    for (int l = 0; l < 25; ++l) {
      float d = ((float)(l - 12) - p) * (1.f / 12.f);
      S += expf(-0.5f * d * d);
    }
    float v = p * (1.f / 12.f);
    float g = w * expf(-0.5f * v * v) / (S + 1e-7f);
    // modified Bessel I_r(v), r = 0..3, 7-term series (|v|<=1)
    float h = 0.5f * v, hh = h * h;
    float pw = 1.f;  // h^r / r!
#pragma unroll
    for (int r = 0; r < R_RANK; ++r) {
      float term = pw, sum = pw;
#pragma unroll
      for (int m = 1; m <= 6; ++m) {
        term *= hh / (float)(m * (m + r));
        sum += term;
      }
      float c = g * ((r == 0) ? 1.f : 2.f) * sum;
      Wr[((size_t)r * COUTP + o) * CINP + i] = (__bf16)c;
      pw *= h / (float)(r + 1);
    }
  }
}

__global__ void setup_all(const float* __restrict__ x,
                          const float* __restrict__ W1, const float* __restrict__ P1,
                          const float* __restrict__ W2, const float* __restrict__ P2,
                          const float* __restrict__ W3, const float* __restrict__ P3,
                          __bf16* __restrict__ Xb, __bf16* __restrict__ Wr1,
                          __bf16* __restrict__ Wr2, __bf16* __restrict__ Wr3,
                          __bf16* __restrict__ Af, float* __restrict__ stats) {
  int blk = blockIdx.x;
  if (blk < 256) { build_wr_body(W1, P1, Wr1, 700, 704, 256, 256, blk); return; }
  blk -= 256;
  if (blk < 256) { build_wr_body(W2, P2, Wr2, 256, 256, 256, 256, blk); return; }
  blk -= 256;
  if (blk < 32) { build_wr_body(W3, P3, Wr3, 256, 256, 20, 32, blk); return; }
  blk -= 32;
  if (blk < 196) {  // Afir (112 x 448): [t][r*100+s] = PHI[s-t+24][r], else 0
    int idx = blk * 256 + threadIdx.x;
    if (idx < 112 * 448) {
      int t = idx / 448, k = idx - t * 448;
      float v = 0.f;
      if (t < 100 && k < 400) {
        int r = k / 100, s = k - r * 100;
        int tau = s - t + 24;
        if (tau >= 0 && tau < 25) v = PHI.v[tau][r];
      }
      Af[idx] = (__bf16)v;
    }
    return;
  }
  blk -= 196;
  if (blk < 2200) {  // x (B,T,700) f32 -> Xb (T,B,704) bf16, vectorized.
    // chunk = 4 cols; 176 chunks/row (chunk 175 = pad), 12800 rows.
    // 2200 blocks * 256 thr * 4 chunks = 2,252,800 = 12800*176 exact cover.
    int c0 = blk * 1024 + threadIdx.x;
#pragma unroll
    for (int k = 0; k < 4; ++k) {
      int c = c0 + k * 256;
      int row = c / 176, col4 = c - row * 176;
      int t = row >> 7, b = row & 127;
      uint2 pk;
      __bf16* pb = (__bf16*)&pk;
      if (col4 < 175) {
        const float* src = x + ((size_t)b * T_LEN + t) * 700 + col4 * 4;
        float4 v = *(const float4*)src;   // 16B-aligned: row base 2800B, +16B
        pb[0] = (__bf16)v.x; pb[1] = (__bf16)v.y;
        pb[2] = (__bf16)v.z; pb[3] = (__bf16)v.w;
      } else {
        pk.x = 0u; pk.y = 0u;
      }
      *(uint2*)&Xb[(size_t)row * 704 + col4 * 4] = pk;
    }
    return;
  }
  blk -= 2200;
  if (blk == 0) {
    for (int i = threadIdx.x; i < 1024; i += 256) stats[i] = 0.f;
  }
}

// ---------------------------------------------------------------------------
// Main GEMM, BK=64: Z[k=(r,t)][n=(b,o)] = A @ Wr^T.
// Counted-wait pipeline (R13-proven pattern): B (weights, the larger stream,
// 8 DMA/thread) double-buffered so B(i+1) is in flight across compute(i);
// A (4 DMA/thread, L3-warm Xb) staged+waited per iter. Steady-state wait is
// vmcnt(B_ISSUES) -- never a full drain except the last iter.
// LDS: 16K sA + 2x BLK_N*128B sB (BLK_N=256: 80KB exact = 160K/2 -> 2 blk/CU).
// ---------------------------------------------------------------------------
template <int CINP, int BLK_N, int WROWS, int WCOLS, int CO_SH>
__global__ __launch_bounds__(256, 2)
void gemm_rk64(const __bf16* __restrict__ A, const __bf16* __restrict__ Bm,
               __bf16* __restrict__ Z) {
  constexpr int COUTP = 1 << CO_SH;
  constexpr int WM = 128 / WROWS;
  constexpr int WN = BLK_N / WCOLS;
  constexpr int RM = WM / 16;
  constexpr int RN = WN / 16;
  constexpr int NITER = CINP / 64;
  __shared__ __align__(16) __bf16 sA[128 * 64];
  __shared__ __align__(16) __bf16 sB[2][BLK_N * 64];

  const int tid = threadIdx.x;
  const int w = tid >> 6, lane = tid & 63;
  const int q = lane >> 4, ln = lane & 15;
  const int wrow = w / WCOLS, wcol = w % WCOLS;
  const int srow8 = lane >> 3;
  const int s8 = lane & 7;

  const int t0 = blockIdx.x;
  const int oc = blockIdx.y * BLK_N;
  const __bf16* Abase = A + (size_t)t0 * 128 * CINP;
  const __bf16* Bbase = Bm + (size_t)oc * CINP;

  v4f acc[RM][RN];
#pragma unroll
  for (int a = 0; a < RM; ++a)
#pragma unroll
    for (int b = 0; b < RN; ++b) acc[a][b] = v4f{0.f, 0.f, 0.f, 0.f};

  // prologue: issue B(0)
  for (int j = w; j < BLK_N / 8; j += 4) {
    int n = j * 8 + srow8;
    int g = s8 ^ (n & 7);
    gl_lds16(Bbase + (size_t)n * CINP + 0 + g * 8, &sB[0][j * 512]);
  }

  for (int i = 0; i < NITER; ++i) {
    const int ic = i * 64;
    // stage A(i) (waited below together with B(i))
    for (int j = w; j < 16; j += 4) {
      int m = j * 8 + srow8;
      int g = s8 ^ (m & 7);
      gl_lds16(Abase + (size_t)m * CINP + ic + g * 8, &sA[j * 512]);
    }
    // issue B(i+1) into the other buffer (stays in flight across compute(i))
    if (i + 1 < NITER) {
      const int icn = ic + 64;
      for (int j = w; j < BLK_N / 8; j += 4) {
        int n = j * 8 + srow8;
        int g = s8 ^ (n & 7);
        gl_lds16(Bbase + (size_t)n * CINP + icn + g * 8, &sB[(i + 1) & 1][j * 512]);
      }
      // wait A(i)+B(i); allow B(i+1)'s issues (per-thread count = BLK_N/32)
      if constexpr (BLK_N == 256) {
        asm volatile("s_waitcnt vmcnt(8)" ::: "memory");
      } else {
        asm volatile("s_waitcnt vmcnt(2)" ::: "memory");
      }
    } else {
      asm volatile("s_waitcnt vmcnt(0)" ::: "memory");
    }
    __builtin_amdgcn_s_barrier();

    const __bf16* sBc = sB[i & 1];
#pragma unroll
    for (int s = 0; s < 2; ++s) {
      v8bf af[RM], bfr[RN];
#pragma unroll
      for (int a = 0; a < RM; ++a) {
        int m = wrow * WM + a * 16 + ln;
        af[a] = *(const v8bf*)&sA[m * 64 + ((((s << 2) | q) ^ (m & 7)) * 8)];
      }
#pragma unroll
      for (int b = 0; b < RN; ++b) {
        int n = wcol * WN + b * 16 + ln;
        bfr[b] = *(const v8bf*)&sBc[n * 64 + ((((s << 2) | q) ^ (n & 7)) * 8)];
      }
#pragma unroll
      for (int a = 0; a < RM; ++a)
#pragma unroll
        for (int b = 0; b < RN; ++b)
          acc[a][b] = __builtin_amdgcn_mfma_f32_16x16x32_bf16(af[a], bfr[b], acc[a][b], 0, 0, 0);
    }
    __builtin_amdgcn_s_barrier();  // protect sA + sB[(i+1)&1] reuse
  }

  // C/D: col=lane&15, row=quad*4+reg (m89-verified)
#pragma unroll
  for (int a = 0; a < RM; ++a) {
#pragma unroll
    for (int b = 0; b < RN; ++b) {
      int n = oc + wcol * WN + b * 16 + ln;
      int r = n >> CO_SH, o = n & (COUTP - 1);
#pragma unroll
      for (int rr = 0; rr < 4; ++rr) {
        int m = t0 * 128 + wrow * WM + a * 16 + q * 4 + rr;
        Z[((size_t)r * M_ROWS + m) * COUTP + o] = (__bf16)acc[a][b][rr];
      }
    }
  }
}

// ---------------------------------------------------------------------------
// FIR GEMM, BK=64, K=448: Y(112 x 64-slice) = Afir(112x448) @ Z(448xN).
// B transposed in LDS (k-pair packed b32, [n][35-dword stride]).
// Double-buffered (2x23296B), counted-wait pipeline (R13). Z rows 400..447
// are never written by gemm (poison) and hit only Afir zeros -- masked to
// zero at stage time: removes ~3MB poison reads/dispatch (wave-uniform
// branch, numerically identical).
// STATS: fused BN sum/sumsq atomics.  SOFTMAX (L3): in-LDS softmax + t-sum.
// ---------------------------------------------------------------------------
template <int COUTP, bool STATS, bool SOFTMAX>
__global__ __launch_bounds__(256, 2)
void fir_gemm64(const __bf16* __restrict__ Af, const __bf16* __restrict__ Z,
                __bf16* __restrict__ Yout, float* __restrict__ stats,
                float* __restrict__ outp, int N) {
  __shared__ __align__(16) unsigned char smem[46592];  // 2 x (14336 + 8960)

  const int tid = threadIdx.x;
  const int w = tid >> 6, lane = tid & 63;
  const int q = lane >> 4, ln = lane & 15;
  const int srow8 = lane >> 3, s8 = lane & 7;
  const int kp = tid >> 3;    // 0..31
  const int noct = tid & 7;   // 0..7
  const int nb = blockIdx.x * 64;

  v4f acc[7];
#pragma unroll
  for (int a = 0; a < 7; ++a) acc[a] = v4f{0.f, 0.f, 0.f, 0.f};

  uint4 r0, r1;  // B-regs for the tile about to be written to LDS

  // buffer b: sA = smem + b*23296 (14336 B), sBu = smem + b*23296 + 14336
#define SA_BUF(b) ((__bf16*)(smem + (b) * 23296))
#define SB_BUF(b) ((uint32*)(smem + (b) * 23296 + 14336))

  // ---- prologue: issue tile 0 (k = kp*2 < 64 < 400: always valid) ----
  {
    __bf16* sA = SA_BUF(0);
    for (int j = w; j < 14; j += 4) {
      int m = j * 8 + srow8;
      int g = s8 ^ (m & 7);
      gl_lds16(Af + (size_t)m * K_FIR + 0 + g * 8, &sA[j * 512]);
    }
    const __bf16* zp = Z + (size_t)(0 + kp * 2) * N + nb + noct * 8;
    r0 = *(const uint4*)zp;
    r1 = *(const uint4*)(zp + N);
  }

  for (int i = 0; i < 7; ++i) {
    const int cb = i & 1;
    // wait: tile i's A-DMA + B-regs (issued one compute-phase ago)
    asm volatile("s_waitcnt vmcnt(0)" ::: "memory");
    // write B(i) -> LDS (transposed, k-pair packed)
    {
      uint32* sBu = SB_BUF(cb);
      const ushort_t* p0 = (const ushort_t*)&r0;
      const ushort_t* p1 = (const ushort_t*)&r1;
#pragma unroll
      for (int j = 0; j < 8; ++j) {
        uint32 val = (uint32)p0[j] | ((uint32)p1[j] << 16);
        sBu[(noct * 8 + j) * 35 + kp] = val;
      }
    }
    // issue tile i+1 (in flight across compute(i))
    if (i < 6) {
      int kc = (i + 1) * 64;
      __bf16* sA = SA_BUF(cb ^ 1);
      for (int j = w; j < 14; j += 4) {
        int m = j * 8 + srow8;
        int g = s8 ^ (m & 7);
        gl_lds16(Af + (size_t)m * K_FIR + kc + g * 8, &sA[j * 512]);
      }
      if (kc + kp * 2 < 400) {  // wave-uniform; masks poison rows 400..447
        const __bf16* zp = Z + (size_t)(kc + kp * 2) * N + nb + noct * 8;
        r0 = *(const uint4*)zp;
        r1 = *(const uint4*)(zp + N);
      } else {
        r0 = uint4{0u, 0u, 0u, 0u};
        r1 = uint4{0u, 0u, 0u, 0u};
      }
    }
    asm volatile("s_waitcnt lgkmcnt(0)" ::: "memory");  // our ds_writes done
    __builtin_amdgcn_s_barrier();                       // raw: no vmcnt drain

    {
      __bf16* sA = SA_BUF(cb);
      uint32* sBu = SB_BUF(cb);
#pragma unroll
      for (int s = 0; s < 2; ++s) {
        v8bf af[7];
#pragma unroll
        for (int a = 0; a < 7; ++a) {
          int m = a * 16 + ln;
          af[a] = *(const v8bf*)&sA[m * 64 + ((((s << 2) | q) ^ (m & 7)) * 8)];
        }
        int base = (w * 16 + ln) * 35 + s * 16 + q * 4;
        uint32 tmp[4] = {sBu[base], sBu[base + 1], sBu[base + 2], sBu[base + 3]};
        v8bf bfr = *(const v8bf*)tmp;
#pragma unroll
        for (int a = 0; a < 7; ++a)
          acc[a] = __builtin_amdgcn_mfma_f32_16x16x32_bf16(af[a], bfr, acc[a], 0, 0, 0);
      }
    }
    __builtin_amdgcn_s_barrier();  // all waves done reading before buf reuse
  }

  int ng = nb + w * 16 + ln;
  if (!SOFTMAX) {
    float s = 0.f, ss = 0.f;
#pragma unroll
    for (int a = 0; a < 7; ++a) {
#pragma unroll
      for (int rr = 0; rr < 4; ++rr) {
        int t = a * 16 + q * 4 + rr;
        float v = acc[a][rr];
        if (t < 100) {
          Yout[(size_t)t * N + ng] = (__bf16)v;
          s += v; ss += v * v;
        }
      }
    }
    if (STATS) {
      s += __shfl_xor(s, 16); ss += __shfl_xor(ss, 16);
      s += __shfl_xor(s, 32); ss += __shfl_xor(ss, 32);
      if (q == 0) {
        int o = ng & (COUTP - 1);
        atomicAdd(&stats[o], s);
        atomicAdd(&stats[COUTP + o], ss);
      }
    }
  } else {
    // L3: this block holds all t and all o for 2 batch entries.
    float* smx = (float*)smem;               // [100][65] = 26000 B (reuses bufs)
    float* lacc = (float*)(smem + 26000);    // 40 floats
    int col = w * 16 + ln;
#pragma unroll
    for (int a = 0; a < 7; ++a) {
#pragma unroll
      for (int rr = 0; rr < 4; ++rr) {
        int t = a * 16 + q * 4 + rr;
        if (t < 100) smx[t * 65 + col] = acc[a][rr];
      }
    }
    if (tid < 64) lacc[tid & 63] = 0.f;
    __syncthreads();
    if (tid < 200) {
      int bl = tid / 100, t = tid - bl * 100;
      const float* rr = &smx[t * 65 + bl * 32];
      float v[20], m = -1e30f;
#pragma unroll
      for (int o = 0; o < 20; ++o) { v[o] = rr[o]; m = fmaxf(m, v[o]); }
      float sum = 0.f;
#pragma unroll
      for (int o = 0; o < 20; ++o) { v[o] = expf(v[o] - m); sum += v[o]; }
      float inv = 1.f / sum;
#pragma unroll
      for (int o = 0; o < 20; ++o) atomicAdd(&lacc[bl * 20 + o], v[o] * inv);
    }
    __syncthreads();
    if (tid < 40) {
      int bl = tid / 20, o = tid - bl * 20;
      int b = (nb >> 5) + bl;
      outp[b * 20 + o] = lacc[bl * 20 + o];
    }
  }
#undef SA_BUF
#undef SB_BUF
}

// normalize + relu, bf16x8 vectorized, in-place on Y
__global__ __launch_bounds__(256)
void bn_apply_relu8(__bf16* __restrict__ h, const float* __restrict__ stats,
                    const float* __restrict__ gamma, const float* __restrict__ beta) {
  int idx = blockIdx.x * 256 + threadIdx.x;
  int co = (idx & 31) * 8;
  size_t row = (size_t)(idx >> 5);
  __bf16* p = h + row * 256 + co;
  uint4 raw = *(const uint4*)p;
  const ushort_t* pr = (const ushort_t*)&raw;
  uint4 outv;
  ushort_t* po = (ushort_t*)&outv;
#pragma unroll
  for (int j = 0; j < 8; ++j) {
    int c = co + j;
    float mean = stats[c] * (1.f / 12800.f);
    float var = stats[256 + c] * (1.f / 12800.f) - mean * mean;
    float inv = rsqrtf(var + 1e-5f) * gamma[c];
    uint32 u = (uint32)pr[j] << 16;
    float xv; __builtin_memcpy(&xv, &u, 4);
    float v = (xv - mean) * inv + beta[c];
    v = fmaxf(v, 0.f);
    __bf16 bv = (__bf16)v;
    po[j] = *(const ushort_t*)&bv;
  }
  *(uint4*)p = outv;
}

// ---------------------------------------------------------------------------

extern "C" void kernel_launch(void* const* d_in, const int* in_sizes, int n_in,
                              void* d_out, int out_size, void* d_ws, size_t ws_size,
                              hipStream_t stream) {
  const float* x  = (const float*)d_in[0];
  const float* W1 = (const float*)d_in[1];
  const float* P1 = (const float*)d_in[2];
  const float* W2 = (const float*)d_in[3];
  const float* P2 = (const float*)d_in[4];
  const float* W3 = (const float*)d_in[5];
  const float* P3 = (const float*)d_in[6];
  const float* g1 = (const float*)d_in[7];
  const float* b1 = (const float*)d_in[8];
  const float* g2 = (const float*)d_in[9];
  const float* b2 = (const float*)d_in[10];
  float* out = (float*)d_out;

  constexpr size_t XB_B  = (size_t)M_ROWS * 704 * 2;        // 18,022,400
  constexpr size_t Z_B   = (size_t)K_FIR * 32768 * 2;       // 29,360,128
  constexpr size_t Y12_B = (size_t)M_ROWS * 256 * 2;        //  6,553,600
  constexpr size_t W1_B  = (size_t)R_RANK * 256 * 704 * 2;  //  1,441,792
  constexpr size_t W2_B  = (size_t)R_RANK * 256 * 256 * 2;  //    524,288
  constexpr size_t W3_B  = (size_t)R_RANK * 32 * 256 * 2;   //     65,536
  constexpr size_t AF_B  = (size_t)112 * K_FIR * 2;         //    100,352
  constexpr size_t ST_B  = 4096;
  constexpr size_t TOTAL = XB_B + Z_B + Y12_B + W1_B + W2_B + W3_B + AF_B + ST_B;
  if (ws_size < TOTAL) return;

  char* ws = (char*)d_ws;
  size_t off = 0;
  __bf16* Xb   = (__bf16*)(ws + off); off += XB_B;
  __bf16* Zb   = (__bf16*)(ws + off); off += Z_B;
  __bf16* Yb   = (__bf16*)(ws + off); off += Y12_B;   // Y1 then Y2 (in-place BN)
  __bf16* Wr1  = (__bf16*)(ws + off); off += W1_B;
  __bf16* Wr2  = (__bf16*)(ws + off); off += W2_B;
  __bf16* Wr3  = (__bf16*)(ws + off); off += W3_B;
  __bf16* Afir = (__bf16*)(ws + off); off += AF_B;
  float*  stats1 = (float*)(ws + off);
  float*  stats2 = stats1 + 512;

  // fused setup: 256+256+32+196+2200+1 blocks
  setup_all<<<dim3(2941), 256, 0, stream>>>(x, W1, P1, W2, P2, W3, P3,
                                            Xb, Wr1, Wr2, Wr3, Afir, stats1);

  // layer 1: GEMM (12800 x 1024 x 704), BLK_N=256 -> FIR (+stats) -> BN in-place
  gemm_rk64<704, 256, 2, 2, 8><<<dim3(100, 4), 256, 0, stream>>>(Xb, Wr1, Zb);
  fir_gemm64<256, true, false><<<dim3(512), 256, 0, stream>>>(
      Afir, Zb, Yb, stats1, nullptr, 32768);
  bn_apply_relu8<<<dim3(1600), 256, 0, stream>>>(Yb, stats1, g1, b1);

  // layer 2: GEMM (12800 x 1024 x 256), BLK_N=256
  gemm_rk64<256, 256, 2, 2, 8><<<dim3(100, 4), 256, 0, stream>>>(Yb, Wr2, Zb);
  fir_gemm64<256, true, false><<<dim3(512), 256, 0, stream>>>(
      Afir, Zb, Yb, stats2, nullptr, 32768);
  bn_apply_relu8<<<dim3(1600), 256, 0, stream>>>(Yb, stats2, g2, b2);

  // layer 3: GEMM (12800 x 128 x 256), then FIR + fused softmax/time-sum
  gemm_rk64<256, 64, 2, 2, 5><<<dim3(100, 2), 256, 0, stream>>>(Yb, Wr3, Zb);
  fir_gemm64<32, false, true><<<dim3(64), 256, 0, stream>>>(
      Afir, Zb, nullptr, nullptr, out, 4096);
}

// Round 5
// 193.077 us; speedup vs baseline: 1.0013x; 1.0013x over previous
//
#include <hip/hip_runtime.h>
#include <stdint.h>

// ---------------------------------------------------------------------------
// d128snn_delays, round 15 = R13 gemm revert + fir poison-mask (kept from
// R14) + coalesced Z-write via LDS repack in gemm (CO_SH==8 only).
// Measured-dead-end ledger:
//   - inline BN in GEMM staging (R6): +VALU in K-loop critical path, net -.
//   - cooperative mega-kernel (R9): grid.sync() ~110us each on gfx950 -> 5x.
//   - XCD-aware swizzle (R10): serializes A-fill through one XCD's L2. -10us.
//   - R12 device-scope semaphore BN fusion: +55us PER SYNC (fir 77us,
//     MfmaUtil 1.5%, 95% spin). ANY grid-wide sync on gfx950 ~ +55us. Never.
//   - R14 gemm dbuf-B: +4.5us. A(i) still issued right before the wait ->
//     same exposed latency as full drain, but LDS 48->80KB cut co-residency.
//     Half-pipelines that issue one stream synchronously gain nothing.
// R13 (dbuf fir + vec setup): 198.7 -> 188.8us, matched prediction.
// Budget: ~42us harness fill + ~77us kernels + ~45us dispatch gaps.
// ---------------------------------------------------------------------------

#define T_LEN 100
#define B_SZ  128
#define M_ROWS 12800
#define R_RANK 4
#define K_FIR 448

typedef __bf16 v8bf __attribute__((ext_vector_type(8)));
typedef float  v4f  __attribute__((ext_vector_type(4)));
typedef unsigned int uint32;
typedef unsigned short ushort_t;

// PHI[tau][r] = exp(-u^2/2) * T_r(u), u = (tau-12)/12  (Chebyshev basis)
struct PhiT { float v[25][R_RANK]; };
constexpr double cexp_(double x) {
  double s = 1.0, t = 1.0;
  for (int n = 1; n < 30; ++n) { t = t * x / n; s += t; }
  return s;
}
constexpr PhiT make_phi() {
  PhiT P{};
  for (int tau = 0; tau < 25; ++tau) {
    double u = (tau - 12) / 12.0;
    double g = cexp_(-0.5 * u * u);
    double T0 = 1.0, T1 = u;
    P.v[tau][0] = (float)(g * T0);
    P.v[tau][1] = (float)(g * T1);
    for (int r = 2; r < R_RANK; ++r) {
      double T2 = 2.0 * u * T1 - T0;
      P.v[tau][r] = (float)(g * T2);
      T0 = T1; T1 = T2;
    }
  }
  return P;
}
constexpr PhiT PHI = make_phi();

__device__ __forceinline__ void gl_lds16(const void* g, void* l) {
  __builtin_amdgcn_global_load_lds(
      (const __attribute__((address_space(1))) char*)g,
      (__attribute__((address_space(3))) char*)l, 16, 0, 0);
}

// ---------------------------------------------------------------------------
// Fused setup: 3x build_wr (Chebyshev/Bessel coeffs) + build_afir + fill_xb
// (vectorized: float4 loads, 8B bf16x4 stores) + stats zero.
// ---------------------------------------------------------------------------
__device__ __forceinline__ void build_wr_body(
    const float* __restrict__ W, const float* __restrict__ P,
    __bf16* __restrict__ Wr, int CIN, int CINP, int COUT, int COUTP, int o) {
  for (int i = threadIdx.x; i < CINP; i += blockDim.x) {
    bool valid = (o < COUT) && (i < CIN);
    float w = valid ? W[(size_t)o * CIN + i] : 0.f;
    float p = valid ? P[(size_t)o * CIN + i] : 0.f;
    float S = 0.f;
#pragma unroll
    for (int l = 0; l < 25; ++l) {
      float d = ((float)(l - 12) - p) * (1.f / 12.f);
      S += expf(-0.5f * d * d);
    }
    float v = p * (1.f / 12.f);
    float g = w * expf(-0.5f * v * v) / (S + 1e-7f);
    // modified Bessel I_r(v), r = 0..3, 7-term series (|v|<=1)
    float h = 0.5f * v, hh = h * h;
    float pw = 1.f;  // h^r / r!
#pragma unroll
    for (int r = 0; r < R_RANK; ++r) {
      float term = pw, sum = pw;
#pragma unroll
      for (int m = 1; m <= 6; ++m) {
        term *= hh / (float)(m * (m + r));
        sum += term;
      }
      float c = g * ((r == 0) ? 1.f : 2.f) * sum;
      Wr[((size_t)r * COUTP + o) * CINP + i] = (__bf16)c;
      pw *= h / (float)(r + 1);
    }
  }
}

__global__ void setup_all(const float* __restrict__ x,
                          const float* __restrict__ W1, const float* __restrict__ P1,
                          const float* __restrict__ W2, const float* __restrict__ P2,
                          const float* __restrict__ W3, const float* __restrict__ P3,
                          __bf16* __restrict__ Xb, __bf16* __restrict__ Wr1,
                          __bf16* __restrict__ Wr2, __bf16* __restrict__ Wr3,
                          __bf16* __restrict__ Af, float* __restrict__ stats) {
  int blk = blockIdx.x;
  if (blk < 256) { build_wr_body(W1, P1, Wr1, 700, 704, 256, 256, blk); return; }
  blk -= 256;
  if (blk < 256) { build_wr_body(W2, P2, Wr2, 256, 256, 256, 256, blk); return; }
  blk -= 256;
  if (blk < 32) { build_wr_body(W3, P3, Wr3, 256, 256, 20, 32, blk); return; }
  blk -= 32;
  if (blk < 196) {  // Afir (112 x 448): [t][r*100+s] = PHI[s-t+24][r], else 0
    int idx = blk * 256 + threadIdx.x;
    if (idx < 112 * 448) {
      int t = idx / 448, k = idx - t * 448;
      float v = 0.f;
      if (t < 100 && k < 400) {
        int r = k / 100, s = k - r * 100;
        int tau = s - t + 24;
        if (tau >= 0 && tau < 25) v = PHI.v[tau][r];
      }
      Af[idx] = (__bf16)v;
    }
    return;
  }
  blk -= 196;
  if (blk < 2200) {  // x (B,T,700) f32 -> Xb (T,B,704) bf16, vectorized.
    // chunk = 4 cols; 176 chunks/row (chunk 175 = pad), 12800 rows.
    // 2200 blocks * 256 thr * 4 chunks = 2,252,800 = 12800*176 exact cover.
    int c0 = blk * 1024 + threadIdx.x;
#pragma unroll
    for (int k = 0; k < 4; ++k) {
      int c = c0 + k * 256;
      int row = c / 176, col4 = c - row * 176;
      int t = row >> 7, b = row & 127;
      uint2 pk;
      __bf16* pb = (__bf16*)&pk;
      if (col4 < 175) {
        const float* src = x + ((size_t)b * T_LEN + t) * 700 + col4 * 4;
        float4 v = *(const float4*)src;   // 16B-aligned: row base 2800B, +16B
        pb[0] = (__bf16)v.x; pb[1] = (__bf16)v.y;
        pb[2] = (__bf16)v.z; pb[3] = (__bf16)v.w;
      } else {
        pk.x = 0u; pk.y = 0u;
      }
      *(uint2*)&Xb[(size_t)row * 704 + col4 * 4] = pk;
    }
    return;
  }
  blk -= 2200;
  if (blk == 0) {
    for (int i = threadIdx.x; i < 1024; i += 256) stats[i] = 0.f;
  }
}

// ---------------------------------------------------------------------------
// Main GEMM, BK=64 (R13-exact K-loop): Z[k=(r,t)][n=(b,o)] = A @ Wr^T.
// Pure async-DMA staging, single-buffered, LDS [row][64] XOR-swizzled.
// Epilogue (CO_SH==8): LDS repack -> coalesced 512B-row dwordx4 Z stores
// (old path: 128 scalar 2B stores/thread = 32B segments). CO_SH==5 keeps
// scalar path (r varies within a row; tensor is 8x smaller).
// ---------------------------------------------------------------------------
template <int CINP, int BLK_N, int WROWS, int WCOLS, int CO_SH>
__global__ __launch_bounds__(256, 2)
void gemm_rk64(const __bf16* __restrict__ A, const __bf16* __restrict__ Bm,
               __bf16* __restrict__ Z) {
  constexpr int COUTP = 1 << CO_SH;
  constexpr int WM = 128 / WROWS;
  constexpr int WN = BLK_N / WCOLS;
  constexpr int RM = WM / 16;
  constexpr int RN = WN / 16;
  __shared__ __align__(16) unsigned char smem[16384 + BLK_N * 128];
  __bf16* sA = (__bf16*)smem;
  __bf16* sB = (__bf16*)(smem + 16384);

  const int tid = threadIdx.x;
  const int w = tid >> 6, lane = tid & 63;
  const int q = lane >> 4, ln = lane & 15;
  const int wrow = w / WCOLS, wcol = w % WCOLS;
  const int srow8 = lane >> 3;
  const int s8 = lane & 7;

  const int t0 = blockIdx.x;
  const int oc = blockIdx.y * BLK_N;
  const __bf16* Abase = A + (size_t)t0 * 128 * CINP;
  const __bf16* Bbase = Bm + (size_t)oc * CINP;

  v4f acc[RM][RN];
#pragma unroll
  for (int a = 0; a < RM; ++a)
#pragma unroll
    for (int b = 0; b < RN; ++b) acc[a][b] = v4f{0.f, 0.f, 0.f, 0.f};

  for (int ic = 0; ic < CINP; ic += 64) {
    for (int j = w; j < 16; j += 4) {  // A: 128 rows, 8 rows/issue
      int m = j * 8 + srow8;
      int g = s8 ^ (m & 7);
      gl_lds16(Abase + (size_t)m * CINP + ic + g * 8, &sA[j * 512]);
    }
    for (int j = w; j < BLK_N / 8; j += 4) {  // B
      int n = j * 8 + srow8;
      int g = s8 ^ (n & 7);
      gl_lds16(Bbase + (size_t)n * CINP + ic + g * 8, &sB[j * 512]);
    }
    __syncthreads();

#pragma unroll
    for (int s = 0; s < 2; ++s) {
      v8bf af[RM], bfr[RN];
#pragma unroll
      for (int a = 0; a < RM; ++a) {
        int m = wrow * WM + a * 16 + ln;
        af[a] = *(const v8bf*)&sA[m * 64 + ((((s << 2) | q) ^ (m & 7)) * 8)];
      }
#pragma unroll
      for (int b = 0; b < RN; ++b) {
        int n = wcol * WN + b * 16 + ln;
        bfr[b] = *(const v8bf*)&sB[n * 64 + ((((s << 2) | q) ^ (n & 7)) * 8)];
      }
#pragma unroll
      for (int a = 0; a < RM; ++a)
#pragma unroll
        for (int b = 0; b < RN; ++b)
          acc[a][b] = __builtin_amdgcn_mfma_f32_16x16x32_bf16(af[a], bfr[b], acc[a][b], 0, 0, 0);
    }
    __syncthreads();
  }

  // C/D fragment: col=lane&15, row=quad*4+reg (m89-verified)
  if constexpr (CO_SH == 8) {
    // r is block-uniform (oc = by*256). Repack per a-chunk through LDS:
    // [32][264] bf16 (16.9KB, fits dead sA+sB), then 2x512B/wave stores.
    const int r = blockIdx.y;
    __bf16* sT = (__bf16*)smem;
#pragma unroll
    for (int a = 0; a < RM; ++a) {
      __syncthreads();  // previous chunk (or K-loop LDS) fully consumed
#pragma unroll
      for (int b = 0; b < RN; ++b) {
        int col = wcol * WN + b * 16 + ln;
#pragma unroll
        for (int rr = 0; rr < 4; ++rr) {
          int lr = wrow * 16 + q * 4 + rr;
          sT[lr * 264 + col] = (__bf16)acc[a][b][rr];
        }
      }
      __syncthreads();
#pragma unroll
      for (int p = 0; p < 4; ++p) {
        int lr = p * 8 + (tid >> 5);
        int slot = tid & 31;
        int m = t0 * 128 + (lr >> 4) * 64 + a * 16 + (lr & 15);
        uint4 v = *(const uint4*)&sT[lr * 264 + slot * 8];
        *(uint4*)&Z[((size_t)r * M_ROWS + m) * 256 + slot * 8] = v;
      }
    }
  } else {
#pragma unroll
    for (int a = 0; a < RM; ++a) {
#pragma unroll
      for (int b = 0; b < RN; ++b) {
        int n = oc + wcol * WN + b * 16 + ln;
        int r = n >> CO_SH, o = n & (COUTP - 1);
#pragma unroll
        for (int rr = 0; rr < 4; ++rr) {
          int m = t0 * 128 + wrow * WM + a * 16 + q * 4 + rr;
          Z[((size_t)r * M_ROWS + m) * COUTP + o] = (__bf16)acc[a][b][rr];
        }
      }
    }
  }
}

// ---------------------------------------------------------------------------
// FIR GEMM, BK=64, K=448: Y(112 x 64-slice) = Afir(112x448) @ Z(448xN).
// B transposed in LDS (k-pair packed b32, [n][35-dword stride]).
// Double-buffered (2x23296B), counted-wait pipeline (R13). Z rows 400..447
// are never written by gemm (poison) and hit only Afir zeros -- masked to
// zero at stage time (wave-uniform branch, numerically identical).
// STATS: fused BN sum/sumsq atomics.  SOFTMAX (L3): in-LDS softmax + t-sum.
// ---------------------------------------------------------------------------
template <int COUTP, bool STATS, bool SOFTMAX>
__global__ __launch_bounds__(256, 2)
void fir_gemm64(const __bf16* __restrict__ Af, const __bf16* __restrict__ Z,
                __bf16* __restrict__ Yout, float* __restrict__ stats,
                float* __restrict__ outp, int N) {
  __shared__ __align__(16) unsigned char smem[46592];  // 2 x (14336 + 8960)

  const int tid = threadIdx.x;
  const int w = tid >> 6, lane = tid & 63;
  const int q = lane >> 4, ln = lane & 15;
  const int srow8 = lane >> 3, s8 = lane & 7;
  const int kp = tid >> 3;    // 0..31
  const int noct = tid & 7;   // 0..7
  const int nb = blockIdx.x * 64;

  v4f acc[7];
#pragma unroll
  for (int a = 0; a < 7; ++a) acc[a] = v4f{0.f, 0.f, 0.f, 0.f};

  uint4 r0, r1;  // B-regs for the tile about to be written to LDS

  // buffer b: sA = smem + b*23296 (14336 B), sBu = smem + b*23296 + 14336
#define SA_BUF(b) ((__bf16*)(smem + (b) * 23296))
#define SB_BUF(b) ((uint32*)(smem + (b) * 23296 + 14336))

  // ---- prologue: issue tile 0 (k = kp*2 < 64 < 400: always valid) ----
  {
    __bf16* sA = SA_BUF(0);
    for (int j = w; j < 14; j += 4) {
      int m = j * 8 + srow8;
      int g = s8 ^ (m & 7);
      gl_lds16(Af + (size_t)m * K_FIR + 0 + g * 8, &sA[j * 512]);
    }
    const __bf16* zp = Z + (size_t)(0 + kp * 2) * N + nb + noct * 8;
    r0 = *(const uint4*)zp;
    r1 = *(const uint4*)(zp + N);
  }

  for (int i = 0; i < 7; ++i) {
    const int cb = i & 1;
    // wait: tile i's A-DMA + B-regs (issued one compute-phase ago)
    asm volatile("s_waitcnt vmcnt(0)" ::: "memory");
    // write B(i) -> LDS (transposed, k-pair packed)
    {
      uint32* sBu = SB_BUF(cb);
      const ushort_t* p0 = (const ushort_t*)&r0;
      const ushort_t* p1 = (const ushort_t*)&r1;
#pragma unroll
      for (int j = 0; j < 8; ++j) {
        uint32 val = (uint32)p0[j] | ((uint32)p1[j] << 16);
        sBu[(noct * 8 + j) * 35 + kp] = val;
      }
    }
    // issue tile i+1 (in flight across compute(i))
    if (i < 6) {
      int kc = (i + 1) * 64;
      __bf16* sA = SA_BUF(cb ^ 1);
      for (int j = w; j < 14; j += 4) {
        int m = j * 8 + srow8;
        int g = s8 ^ (m & 7);
        gl_lds16(Af + (size_t)m * K_FIR + kc + g * 8, &sA[j * 512]);
      }
      if (kc + kp * 2 < 400) {  // wave-uniform; masks poison rows 400..447
        const __bf16* zp = Z + (size_t)(kc + kp * 2) * N + nb + noct * 8;
        r0 = *(const uint4*)zp;
        r1 = *(const uint4*)(zp + N);
      } else {
        r0 = uint4{0u, 0u, 0u, 0u};
        r1 = uint4{0u, 0u, 0u, 0u};
      }
    }
    asm volatile("s_waitcnt lgkmcnt(0)" ::: "memory");  // our ds_writes done
    __builtin_amdgcn_s_barrier();                       // raw: no vmcnt drain

    {
      __bf16* sA = SA_BUF(cb);
      uint32* sBu = SB_BUF(cb);
#pragma unroll
      for (int s = 0; s < 2; ++s) {
        v8bf af[7];
#pragma unroll
        for (int a = 0; a < 7; ++a) {
          int m = a * 16 + ln;
          af[a] = *(const v8bf*)&sA[m * 64 + ((((s << 2) | q) ^ (m & 7)) * 8)];
        }
        int base = (w * 16 + ln) * 35 + s * 16 + q * 4;
        uint32 tmp[4] = {sBu[base], sBu[base + 1], sBu[base + 2], sBu[base + 3]};
        v8bf bfr = *(const v8bf*)tmp;
#pragma unroll
        for (int a = 0; a < 7; ++a)
          acc[a] = __builtin_amdgcn_mfma_f32_16x16x32_bf16(af[a], bfr, acc[a], 0, 0, 0);
      }
    }
    __builtin_amdgcn_s_barrier();  // all waves done reading before buf reuse
  }

  int ng = nb + w * 16 + ln;
  if (!SOFTMAX) {
    float s = 0.f, ss = 0.f;
#pragma unroll
    for (int a = 0; a < 7; ++a) {
#pragma unroll
      for (int rr = 0; rr < 4; ++rr) {
        int t = a * 16 + q * 4 + rr;
        float v = acc[a][rr];
        if (t < 100) {
          Yout[(size_t)t * N + ng] = (__bf16)v;
          s += v; ss += v * v;
        }
      }
    }
    if (STATS) {
      s += __shfl_xor(s, 16); ss += __shfl_xor(ss, 16);
      s += __shfl_xor(s, 32); ss += __shfl_xor(ss, 32);
      if (q == 0) {
        int o = ng & (COUTP - 1);
        atomicAdd(&stats[o], s);
        atomicAdd(&stats[COUTP + o], ss);
      }
    }
  } else {
    // L3: this block holds all t and all o for 2 batch entries.
    float* smx = (float*)smem;               // [100][65] = 26000 B (reuses bufs)
    float* lacc = (float*)(smem + 26000);    // 40 floats
    int col = w * 16 + ln;
#pragma unroll
    for (int a = 0; a < 7; ++a) {
#pragma unroll
      for (int rr = 0; rr < 4; ++rr) {
        int t = a * 16 + q * 4 + rr;
        if (t < 100) smx[t * 65 + col] = acc[a][rr];
      }
    }
    if (tid < 64) lacc[tid & 63] = 0.f;
    __syncthreads();
    if (tid < 200) {
      int bl = tid / 100, t = tid - bl * 100;
      const float* rr = &smx[t * 65 + bl * 32];
      float v[20], m = -1e30f;
#pragma unroll
      for (int o = 0; o < 20; ++o) { v[o] = rr[o]; m = fmaxf(m, v[o]); }
      float sum = 0.f;
#pragma unroll
      for (int o = 0; o < 20; ++o) { v[o] = expf(v[o] - m); sum += v[o]; }
      float inv = 1.f / sum;
#pragma unroll
      for (int o = 0; o < 20; ++o) atomicAdd(&lacc[bl * 20 + o], v[o] * inv);
    }
    __syncthreads();
    if (tid < 40) {
      int bl = tid / 20, o = tid - bl * 20;
      int b = (nb >> 5) + bl;
      outp[b * 20 + o] = lacc[bl * 20 + o];
    }
  }
#undef SA_BUF
#undef SB_BUF
}

// normalize + relu, bf16x8 vectorized, in-place on Y
__global__ __launch_bounds__(256)
void bn_apply_relu8(__bf16* __restrict__ h, const float* __restrict__ stats,
                    const float* __restrict__ gamma, const float* __restrict__ beta) {
  int idx = blockIdx.x * 256 + threadIdx.x;
  int co = (idx & 31) * 8;
  size_t row = (size_t)(idx >> 5);
  __bf16* p = h + row * 256 + co;
  uint4 raw = *(const uint4*)p;
  const ushort_t* pr = (const ushort_t*)&raw;
  uint4 outv;
  ushort_t* po = (ushort_t*)&outv;
#pragma unroll
  for (int j = 0; j < 8; ++j) {
    int c = co + j;
    float mean = stats[c] * (1.f / 12800.f);
    float var = stats[256 + c] * (1.f / 12800.f) - mean * mean;
    float inv = rsqrtf(var + 1e-5f) * gamma[c];
    uint32 u = (uint32)pr[j] << 16;
    float xv; __builtin_memcpy(&xv, &u, 4);
    float v = (xv - mean) * inv + beta[c];
    v = fmaxf(v, 0.f);
    __bf16 bv = (__bf16)v;
    po[j] = *(const ushort_t*)&bv;
  }
  *(uint4*)p = outv;
}

// ---------------------------------------------------------------------------

extern "C" void kernel_launch(void* const* d_in, const int* in_sizes, int n_in,
                              void* d_out, int out_size, void* d_ws, size_t ws_size,
                              hipStream_t stream) {
  const float* x  = (const float*)d_in[0];
  const float* W1 = (const float*)d_in[1];
  const float* P1 = (const float*)d_in[2];
  const float* W2 = (const float*)d_in[3];
  const float* P2 = (const float*)d_in[4];
  const float* W3 = (const float*)d_in[5];
  const float* P3 = (const float*)d_in[6];
  const float* g1 = (const float*)d_in[7];
  const float* b1 = (const float*)d_in[8];
  const float* g2 = (const float*)d_in[9];
  const float* b2 = (const float*)d_in[10];
  float* out = (float*)d_out;

  constexpr size_t XB_B  = (size_t)M_ROWS * 704 * 2;        // 18,022,400
  constexpr size_t Z_B   = (size_t)K_FIR * 32768 * 2;       // 29,360,128
  constexpr size_t Y12_B = (size_t)M_ROWS * 256 * 2;        //  6,553,600
  constexpr size_t W1_B  = (size_t)R_RANK * 256 * 704 * 2;  //  1,441,792
  constexpr size_t W2_B  = (size_t)R_RANK * 256 * 256 * 2;  //    524,288
  constexpr size_t W3_B  = (size_t)R_RANK * 32 * 256 * 2;   //     65,536
  constexpr size_t AF_B  = (size_t)112 * K_FIR * 2;         //    100,352
  constexpr size_t ST_B  = 4096;
  constexpr size_t TOTAL = XB_B + Z_B + Y12_B + W1_B + W2_B + W3_B + AF_B + ST_B;
  if (ws_size < TOTAL) return;

  char* ws = (char*)d_ws;
  size_t off = 0;
  __bf16* Xb   = (__bf16*)(ws + off); off += XB_B;
  __bf16* Zb   = (__bf16*)(ws + off); off += Z_B;
  __bf16* Yb   = (__bf16*)(ws + off); off += Y12_B;   // Y1 then Y2 (in-place BN)
  __bf16* Wr1  = (__bf16*)(ws + off); off += W1_B;
  __bf16* Wr2  = (__bf16*)(ws + off); off += W2_B;
  __bf16* Wr3  = (__bf16*)(ws + off); off += W3_B;
  __bf16* Afir = (__bf16*)(ws + off); off += AF_B;
  float*  stats1 = (float*)(ws + off);
  float*  stats2 = stats1 + 512;

  // fused setup: 256+256+32+196+2200+1 blocks
  setup_all<<<dim3(2941), 256, 0, stream>>>(x, W1, P1, W2, P2, W3, P3,
                                            Xb, Wr1, Wr2, Wr3, Afir, stats1);

  // layer 1: GEMM (12800 x 1024 x 704), BLK_N=256 -> FIR (+stats) -> BN in-place
  gemm_rk64<704, 256, 2, 2, 8><<<dim3(100, 4), 256, 0, stream>>>(Xb, Wr1, Zb);
  fir_gemm64<256, true, false><<<dim3(512), 256, 0, stream>>>(
      Afir, Zb, Yb, stats1, nullptr, 32768);
  bn_apply_relu8<<<dim3(1600), 256, 0, stream>>>(Yb, stats1, g1, b1);

  // layer 2: GEMM (12800 x 1024 x 256), BLK_N=256
  gemm_rk64<256, 256, 2, 2, 8><<<dim3(100, 4), 256, 0, stream>>>(Yb, Wr2, Zb);
  fir_gemm64<256, true, false><<<dim3(512), 256, 0, stream>>>(
      Afir, Zb, Yb, stats2, nullptr, 32768);
  bn_apply_relu8<<<dim3(1600), 256, 0, stream>>>(Yb, stats2, g2, b2);

  // layer 3: GEMM (12800 x 128 x 256), then FIR + fused softmax/time-sum
  gemm_rk64<256, 64, 2, 2, 5><<<dim3(100, 2), 256, 0, stream>>>(Yb, Wr3, Zb);
  fir_gemm64<32, false, true><<<dim3(64), 256, 0, stream>>>(
      Afir, Zb, nullptr, nullptr, out, 4096);
}

// Round 6
// 186.241 us; speedup vs baseline: 1.0380x; 1.0367x over previous
//
#include <hip/hip_runtime.h>
#include <stdint.h>

// ---------------------------------------------------------------------------
// d128snn_delays, round 16 = byte-exact R13 revert (measured 188.8us) as the
// A/B control leg. R14 (dbuf-gemm + fir poison-mask) = 193.3; R15 (repack
// epilogue + fir poison-mask) = 193.1. Two different gemm variants, same
// +4.4us: either the common poison-mask is the regression (prefetch-clause
// split) or the noise band is +-4us. This run decides.
// Measured-dead-end ledger:
//   - inline BN in GEMM staging (R6): +VALU in K-loop critical path, net -.
//   - cooperative mega-kernel (R9): grid.sync() ~110us each on gfx950 -> 5x.
//   - XCD-aware swizzle (R10): serializes A-fill through one XCD's L2. -10us.
//   - R12 device-scope semaphore BN fusion: +55us PER SYNC (fir 77us,
//     MfmaUtil 1.5%, 95% spin). ANY grid-wide sync on gfx950 ~ +55us. Never.
//   - R14 gemm dbuf-B: A(i) still issued right before the wait -> same
//     exposed latency as drain; LDS 48->80KB. Suspect with R15 evidence:
//     the fir poison-mask (shared by R14/R15) may be the real +4us.
//   - R15 coalesced-Z repack epilogue: no gain observed (193.1 w/ mask).
// Budget: ~42us harness fill + ~77us kernels + ~45us dispatch gaps.
// ---------------------------------------------------------------------------

#define T_LEN 100
#define B_SZ  128
#define M_ROWS 12800
#define R_RANK 4
#define K_FIR 448

typedef __bf16 v8bf __attribute__((ext_vector_type(8)));
typedef float  v4f  __attribute__((ext_vector_type(4)));
typedef unsigned int uint32;
typedef unsigned short ushort_t;

// PHI[tau][r] = exp(-u^2/2) * T_r(u), u = (tau-12)/12  (Chebyshev basis)
struct PhiT { float v[25][R_RANK]; };
constexpr double cexp_(double x) {
  double s = 1.0, t = 1.0;
  for (int n = 1; n < 30; ++n) { t = t * x / n; s += t; }
  return s;
}
constexpr PhiT make_phi() {
  PhiT P{};
  for (int tau = 0; tau < 25; ++tau) {
    double u = (tau - 12) / 12.0;
    double g = cexp_(-0.5 * u * u);
    double T0 = 1.0, T1 = u;
    P.v[tau][0] = (float)(g * T0);
    P.v[tau][1] = (float)(g * T1);
    for (int r = 2; r < R_RANK; ++r) {
      double T2 = 2.0 * u * T1 - T0;
      P.v[tau][r] = (float)(g * T2);
      T0 = T1; T1 = T2;
    }
  }
  return P;
}
constexpr PhiT PHI = make_phi();

__device__ __forceinline__ void gl_lds16(const void* g, void* l) {
  __builtin_amdgcn_global_load_lds(
      (const __attribute__((address_space(1))) char*)g,
      (__attribute__((address_space(3))) char*)l, 16, 0, 0);
}

// ---------------------------------------------------------------------------
// Fused setup: 3x build_wr (Chebyshev/Bessel coeffs) + build_afir + fill_xb
// (vectorized: float4 loads, 8B bf16x4 stores) + stats zero.
// ---------------------------------------------------------------------------
__device__ __forceinline__ void build_wr_body(
    const float* __restrict__ W, const float* __restrict__ P,
    __bf16* __restrict__ Wr, int CIN, int CINP, int COUT, int COUTP, int o) {
  for (int i = threadIdx.x; i < CINP; i += blockDim.x) {
    bool valid = (o < COUT) && (i < CIN);
    float w = valid ? W[(size_t)o * CIN + i] : 0.f;
    float p = valid ? P[(size_t)o * CIN + i] : 0.f;
    float S = 0.f;
#pragma unroll
    for (int l = 0; l < 25; ++l) {
      float d = ((float)(l - 12) - p) * (1.f / 12.f);
      S += expf(-0.5f * d * d);
    }
    float v = p * (1.f / 12.f);
    float g = w * expf(-0.5f * v * v) / (S + 1e-7f);
    // modified Bessel I_r(v), r = 0..3, 7-term series (|v|<=1)
    float h = 0.5f * v, hh = h * h;
    float pw = 1.f;  // h^r / r!
#pragma unroll
    for (int r = 0; r < R_RANK; ++r) {
      float term = pw, sum = pw;
#pragma unroll
      for (int m = 1; m <= 6; ++m) {
        term *= hh / (float)(m * (m + r));
        sum += term;
      }
      float c = g * ((r == 0) ? 1.f : 2.f) * sum;
      Wr[((size_t)r * COUTP + o) * CINP + i] = (__bf16)c;
      pw *= h / (float)(r + 1);
    }
  }
}

__global__ void setup_all(const float* __restrict__ x,
                          const float* __restrict__ W1, const float* __restrict__ P1,
                          const float* __restrict__ W2, const float* __restrict__ P2,
                          const float* __restrict__ W3, const float* __restrict__ P3,
                          __bf16* __restrict__ Xb, __bf16* __restrict__ Wr1,
                          __bf16* __restrict__ Wr2, __bf16* __restrict__ Wr3,
                          __bf16* __restrict__ Af, float* __restrict__ stats) {
  int blk = blockIdx.x;
  if (blk < 256) { build_wr_body(W1, P1, Wr1, 700, 704, 256, 256, blk); return; }
  blk -= 256;
  if (blk < 256) { build_wr_body(W2, P2, Wr2, 256, 256, 256, 256, blk); return; }
  blk -= 256;
  if (blk < 32) { build_wr_body(W3, P3, Wr3, 256, 256, 20, 32, blk); return; }
  blk -= 32;
  if (blk < 196) {  // Afir (112 x 448): [t][r*100+s] = PHI[s-t+24][r], else 0
    int idx = blk * 256 + threadIdx.x;
    if (idx < 112 * 448) {
      int t = idx / 448, k = idx - t * 448;
      float v = 0.f;
      if (t < 100 && k < 400) {
        int r = k / 100, s = k - r * 100;
        int tau = s - t + 24;
        if (tau >= 0 && tau < 25) v = PHI.v[tau][r];
      }
      Af[idx] = (__bf16)v;
    }
    return;
  }
  blk -= 196;
  if (blk < 2200) {  // x (B,T,700) f32 -> Xb (T,B,704) bf16, vectorized.
    // chunk = 4 cols; 176 chunks/row (chunk 175 = pad), 12800 rows.
    // 2200 blocks * 256 thr * 4 chunks = 2,252,800 = 12800*176 exact cover.
    int c0 = blk * 1024 + threadIdx.x;
#pragma unroll
    for (int k = 0; k < 4; ++k) {
      int c = c0 + k * 256;
      int row = c / 176, col4 = c - row * 176;
      int t = row >> 7, b = row & 127;
      uint2 pk;
      __bf16* pb = (__bf16*)&pk;
      if (col4 < 175) {
        const float* src = x + ((size_t)b * T_LEN + t) * 700 + col4 * 4;
        float4 v = *(const float4*)src;   // 16B-aligned: row base 2800B, +16B
        pb[0] = (__bf16)v.x; pb[1] = (__bf16)v.y;
        pb[2] = (__bf16)v.z; pb[3] = (__bf16)v.w;
      } else {
        pk.x = 0u; pk.y = 0u;
      }
      *(uint2*)&Xb[(size_t)row * 704 + col4 * 4] = pk;
    }
    return;
  }
  blk -= 2200;
  if (blk == 0) {
    for (int i = threadIdx.x; i < 1024; i += 256) stats[i] = 0.f;
  }
}

// ---------------------------------------------------------------------------
// Main GEMM, BK=64: Z[k=(r,t)][n=(b,o)] = A @ Wr^T. Pure async-DMA staging.
// LDS: [row][64], 8-elem kgroup slot s holds logical group s^(row&7).
// ---------------------------------------------------------------------------
template <int CINP, int BLK_N, int WROWS, int WCOLS, int CO_SH>
__global__ __launch_bounds__(256, 2)
void gemm_rk64(const __bf16* __restrict__ A, const __bf16* __restrict__ Bm,
               __bf16* __restrict__ Z) {
  constexpr int COUTP = 1 << CO_SH;
  constexpr int WM = 128 / WROWS;
  constexpr int WN = BLK_N / WCOLS;
  constexpr int RM = WM / 16;
  constexpr int RN = WN / 16;
  __shared__ __align__(16) __bf16 sA[128 * 64];
  __shared__ __align__(16) __bf16 sB[BLK_N * 64];

  const int tid = threadIdx.x;
  const int w = tid >> 6, lane = tid & 63;
  const int q = lane >> 4, ln = lane & 15;
  const int wrow = w / WCOLS, wcol = w % WCOLS;
  const int srow8 = lane >> 3;
  const int s8 = lane & 7;

  const int t0 = blockIdx.x;
  const int oc = blockIdx.y * BLK_N;
  const __bf16* Abase = A + (size_t)t0 * 128 * CINP;
  const __bf16* Bbase = Bm + (size_t)oc * CINP;

  v4f acc[RM][RN];
#pragma unroll
  for (int a = 0; a < RM; ++a)
#pragma unroll
    for (int b = 0; b < RN; ++b) acc[a][b] = v4f{0.f, 0.f, 0.f, 0.f};

  for (int ic = 0; ic < CINP; ic += 64) {
    for (int j = w; j < 16; j += 4) {  // A: 128 rows, 8 rows/issue
      int m = j * 8 + srow8;
      int g = s8 ^ (m & 7);
      gl_lds16(Abase + (size_t)m * CINP + ic + g * 8, &sA[j * 512]);
    }
    for (int j = w; j < BLK_N / 8; j += 4) {  // B
      int n = j * 8 + srow8;
      int g = s8 ^ (n & 7);
      gl_lds16(Bbase + (size_t)n * CINP + ic + g * 8, &sB[j * 512]);
    }
    __syncthreads();

#pragma unroll
    for (int s = 0; s < 2; ++s) {
      v8bf af[RM], bfr[RN];
#pragma unroll
      for (int a = 0; a < RM; ++a) {
        int m = wrow * WM + a * 16 + ln;
        af[a] = *(const v8bf*)&sA[m * 64 + ((((s << 2) | q) ^ (m & 7)) * 8)];
      }
#pragma unroll
      for (int b = 0; b < RN; ++b) {
        int n = wcol * WN + b * 16 + ln;
        bfr[b] = *(const v8bf*)&sB[n * 64 + ((((s << 2) | q) ^ (n & 7)) * 8)];
      }
#pragma unroll
      for (int a = 0; a < RM; ++a)
#pragma unroll
        for (int b = 0; b < RN; ++b)
          acc[a][b] = __builtin_amdgcn_mfma_f32_16x16x32_bf16(af[a], bfr[b], acc[a][b], 0, 0, 0);
    }
    __syncthreads();
  }

  // C/D: col=lane&15, row=quad*4+reg (m89-verified)
#pragma unroll
  for (int a = 0; a < RM; ++a) {
#pragma unroll
    for (int b = 0; b < RN; ++b) {
      int n = oc + wcol * WN + b * 16 + ln;
      int r = n >> CO_SH, o = n & (COUTP - 1);
#pragma unroll
      for (int rr = 0; rr < 4; ++rr) {
        int m = t0 * 128 + wrow * WM + a * 16 + q * 4 + rr;
        Z[((size_t)r * M_ROWS + m) * COUTP + o] = (__bf16)acc[a][b][rr];
      }
    }
  }
}

// ---------------------------------------------------------------------------
// FIR GEMM, BK=64, K=448: Y(112 x 64-slice) = Afir(112x448) @ Z(448xN).
// B transposed in LDS (k-pair packed b32, [n][35-dword stride]).
// Double-buffered (2x23296B), counted-wait pipeline: next tile's A-DMA and
// B-reg loads are issued before compute(i) and only drained (vmcnt 0) at the
// top of iter i+1 -- one full compute phase of latency hiding. Raw s_barrier
// (not __syncthreads) so the compiler doesn't force a vmcnt(0) drain at the
// barrier. Two barriers/iter protect dbuf reuse (same density as before).
// STATS: fused BN sum/sumsq atomics.  SOFTMAX (L3): in-LDS softmax + t-sum.
// ---------------------------------------------------------------------------
template <int COUTP, bool STATS, bool SOFTMAX>
__global__ __launch_bounds__(256, 2)
void fir_gemm64(const __bf16* __restrict__ Af, const __bf16* __restrict__ Z,
                __bf16* __restrict__ Yout, float* __restrict__ stats,
                float* __restrict__ outp, int N) {
  __shared__ __align__(16) unsigned char smem[46592];  // 2 x (14336 + 8960)

  const int tid = threadIdx.x;
  const int w = tid >> 6, lane = tid & 63;
  const int q = lane >> 4, ln = lane & 15;
  const int srow8 = lane >> 3, s8 = lane & 7;
  const int kp = tid >> 3;    // 0..31
  const int noct = tid & 7;   // 0..7
  const int nb = blockIdx.x * 64;

  v4f acc[7];
#pragma unroll
  for (int a = 0; a < 7; ++a) acc[a] = v4f{0.f, 0.f, 0.f, 0.f};

  uint4 r0, r1;  // B-regs for the tile about to be written to LDS

  // buffer b: sA = smem + b*23296 (14336 B), sBu = smem + b*23296 + 14336
#define SA_BUF(b) ((__bf16*)(smem + (b) * 23296))
#define SB_BUF(b) ((uint32*)(smem + (b) * 23296 + 14336))

  // ---- prologue: issue tile 0 ----
  {
    __bf16* sA = SA_BUF(0);
    for (int j = w; j < 14; j += 4) {
      int m = j * 8 + srow8;
      int g = s8 ^ (m & 7);
      gl_lds16(Af + (size_t)m * K_FIR + 0 + g * 8, &sA[j * 512]);
    }
    const __bf16* zp = Z + (size_t)(0 + kp * 2) * N + nb + noct * 8;
    r0 = *(const uint4*)zp;
    r1 = *(const uint4*)(zp + N);
  }

  for (int i = 0; i < 7; ++i) {
    const int cb = i & 1;
    // wait: tile i's A-DMA + B-regs (issued one compute-phase ago)
    asm volatile("s_waitcnt vmcnt(0)" ::: "memory");
    // write B(i) -> LDS (transposed, k-pair packed)
    {
      uint32* sBu = SB_BUF(cb);
      const ushort_t* p0 = (const ushort_t*)&r0;
      const ushort_t* p1 = (const ushort_t*)&r1;
#pragma unroll
      for (int j = 0; j < 8; ++j) {
        uint32 val = (uint32)p0[j] | ((uint32)p1[j] << 16);
        sBu[(noct * 8 + j) * 35 + kp] = val;
      }
    }
    // issue tile i+1 (in flight across compute(i))
    if (i < 6) {
      int kc = (i + 1) * 64;
      __bf16* sA = SA_BUF(cb ^ 1);
      for (int j = w; j < 14; j += 4) {
        int m = j * 8 + srow8;
        int g = s8 ^ (m & 7);
        gl_lds16(Af + (size_t)m * K_FIR + kc + g * 8, &sA[j * 512]);
      }
      const __bf16* zp = Z + (size_t)(kc + kp * 2) * N + nb + noct * 8;
      r0 = *(const uint4*)zp;
      r1 = *(const uint4*)(zp + N);
    }
    asm volatile("s_waitcnt lgkmcnt(0)" ::: "memory");  // our ds_writes done
    __builtin_amdgcn_s_barrier();                       // raw: no vmcnt drain

    {
      __bf16* sA = SA_BUF(cb);
      uint32* sBu = SB_BUF(cb);
#pragma unroll
      for (int s = 0; s < 2; ++s) {
        v8bf af[7];
#pragma unroll
        for (int a = 0; a < 7; ++a) {
          int m = a * 16 + ln;
          af[a] = *(const v8bf*)&sA[m * 64 + ((((s << 2) | q) ^ (m & 7)) * 8)];
        }
        int base = (w * 16 + ln) * 35 + s * 16 + q * 4;
        uint32 tmp[4] = {sBu[base], sBu[base + 1], sBu[base + 2], sBu[base + 3]};
        v8bf bfr = *(const v8bf*)tmp;
#pragma unroll
        for (int a = 0; a < 7; ++a)
          acc[a] = __builtin_amdgcn_mfma_f32_16x16x32_bf16(af[a], bfr, acc[a], 0, 0, 0);
      }
    }
    __builtin_amdgcn_s_barrier();  // all waves done reading before buf reuse
  }

  int ng = nb + w * 16 + ln;
  if (!SOFTMAX) {
    float s = 0.f, ss = 0.f;
#pragma unroll
    for (int a = 0; a < 7; ++a) {
#pragma unroll
      for (int rr = 0; rr < 4; ++rr) {
        int t = a * 16 + q * 4 + rr;
        float v = acc[a][rr];
        if (t < 100) {
          Yout[(size_t)t * N + ng] = (__bf16)v;
          s += v; ss += v * v;
        }
      }
    }
    if (STATS) {
      s += __shfl_xor(s, 16); ss += __shfl_xor(ss, 16);
      s += __shfl_xor(s, 32); ss += __shfl_xor(ss, 32);
      if (q == 0) {
        int o = ng & (COUTP - 1);
        atomicAdd(&stats[o], s);
        atomicAdd(&stats[COUTP + o], ss);
      }
    }
  } else {
    // L3: this block holds all t and all o for 2 batch entries.
    float* smx = (float*)smem;               // [100][65] = 26000 B (reuses bufs)
    float* lacc = (float*)(smem + 26000);    // 40 floats
    int col = w * 16 + ln;
#pragma unroll
    for (int a = 0; a < 7; ++a) {
#pragma unroll
      for (int rr = 0; rr < 4; ++rr) {
        int t = a * 16 + q * 4 + rr;
        if (t < 100) smx[t * 65 + col] = acc[a][rr];
      }
    }
    if (tid < 64) lacc[tid & 63] = 0.f;
    __syncthreads();
    if (tid < 200) {
      int bl = tid / 100, t = tid - bl * 100;
      const float* rr = &smx[t * 65 + bl * 32];
      float v[20], m = -1e30f;
#pragma unroll
      for (int o = 0; o < 20; ++o) { v[o] = rr[o]; m = fmaxf(m, v[o]); }
      float sum = 0.f;
#pragma unroll
      for (int o = 0; o < 20; ++o) { v[o] = expf(v[o] - m); sum += v[o]; }
      float inv = 1.f / sum;
#pragma unroll
      for (int o = 0; o < 20; ++o) atomicAdd(&lacc[bl * 20 + o], v[o] * inv);
    }
    __syncthreads();
    if (tid < 40) {
      int bl = tid / 20, o = tid - bl * 20;
      int b = (nb >> 5) + bl;
      outp[b * 20 + o] = lacc[bl * 20 + o];
    }
  }
#undef SA_BUF
#undef SB_BUF
}

// normalize + relu, bf16x8 vectorized, in-place on Y
__global__ __launch_bounds__(256)
void bn_apply_relu8(__bf16* __restrict__ h, const float* __restrict__ stats,
                    const float* __restrict__ gamma, const float* __restrict__ beta) {
  int idx = blockIdx.x * 256 + threadIdx.x;
  int co = (idx & 31) * 8;
  size_t row = (size_t)(idx >> 5);
  __bf16* p = h + row * 256 + co;
  uint4 raw = *(const uint4*)p;
  const ushort_t* pr = (const ushort_t*)&raw;
  uint4 outv;
  ushort_t* po = (ushort_t*)&outv;
#pragma unroll
  for (int j = 0; j < 8; ++j) {
    int c = co + j;
    float mean = stats[c] * (1.f / 12800.f);
    float var = stats[256 + c] * (1.f / 12800.f) - mean * mean;
    float inv = rsqrtf(var + 1e-5f) * gamma[c];
    uint32 u = (uint32)pr[j] << 16;
    float xv; __builtin_memcpy(&xv, &u, 4);
    float v = (xv - mean) * inv + beta[c];
    v = fmaxf(v, 0.f);
    __bf16 bv = (__bf16)v;
    po[j] = *(const ushort_t*)&bv;
  }
  *(uint4*)p = outv;
}

// ---------------------------------------------------------------------------

extern "C" void kernel_launch(void* const* d_in, const int* in_sizes, int n_in,
                              void* d_out, int out_size, void* d_ws, size_t ws_size,
                              hipStream_t stream) {
  const float* x  = (const float*)d_in[0];
  const float* W1 = (const float*)d_in[1];
  const float* P1 = (const float*)d_in[2];
  const float* W2 = (const float*)d_in[3];
  const float* P2 = (const float*)d_in[4];
  const float* W3 = (const float*)d_in[5];
  const float* P3 = (const float*)d_in[6];
  const float* g1 = (const float*)d_in[7];
  const float* b1 = (const float*)d_in[8];
  const float* g2 = (const float*)d_in[9];
  const float* b2 = (const float*)d_in[10];
  float* out = (float*)d_out;

  constexpr size_t XB_B  = (size_t)M_ROWS * 704 * 2;        // 18,022,400
  constexpr size_t Z_B   = (size_t)K_FIR * 32768 * 2;       // 29,360,128
  constexpr size_t Y12_B = (size_t)M_ROWS * 256 * 2;        //  6,553,600
  constexpr size_t W1_B  = (size_t)R_RANK * 256 * 704 * 2;  //  1,441,792
  constexpr size_t W2_B  = (size_t)R_RANK * 256 * 256 * 2;  //    524,288
  constexpr size_t W3_B  = (size_t)R_RANK * 32 * 256 * 2;   //     65,536
  constexpr size_t AF_B  = (size_t)112 * K_FIR * 2;         //    100,352
  constexpr size_t ST_B  = 4096;
  constexpr size_t TOTAL = XB_B + Z_B + Y12_B + W1_B + W2_B + W3_B + AF_B + ST_B;
  if (ws_size < TOTAL) return;

  char* ws = (char*)d_ws;
  size_t off = 0;
  __bf16* Xb   = (__bf16*)(ws + off); off += XB_B;
  __bf16* Zb   = (__bf16*)(ws + off); off += Z_B;
  __bf16* Yb   = (__bf16*)(ws + off); off += Y12_B;   // Y1 then Y2 (in-place BN)
  __bf16* Wr1  = (__bf16*)(ws + off); off += W1_B;
  __bf16* Wr2  = (__bf16*)(ws + off); off += W2_B;
  __bf16* Wr3  = (__bf16*)(ws + off); off += W3_B;
  __bf16* Afir = (__bf16*)(ws + off); off += AF_B;
  float*  stats1 = (float*)(ws + off);
  float*  stats2 = stats1 + 512;

  // fused setup: 256+256+32+196+2200+1 blocks
  setup_all<<<dim3(2941), 256, 0, stream>>>(x, W1, P1, W2, P2, W3, P3,
                                            Xb, Wr1, Wr2, Wr3, Afir, stats1);

  // layer 1: GEMM (12800 x 1024 x 704), BLK_N=256 -> FIR (+stats) -> BN in-place
  gemm_rk64<704, 256, 2, 2, 8><<<dim3(100, 4), 256, 0, stream>>>(Xb, Wr1, Zb);
  fir_gemm64<256, true, false><<<dim3(512), 256, 0, stream>>>(
      Afir, Zb, Yb, stats1, nullptr, 32768);
  bn_apply_relu8<<<dim3(1600), 256, 0, stream>>>(Yb, stats1, g1, b1);

  // layer 2: GEMM (12800 x 1024 x 256), BLK_N=256
  gemm_rk64<256, 256, 2, 2, 8><<<dim3(100, 4), 256, 0, stream>>>(Yb, Wr2, Zb);
  fir_gemm64<256, true, false><<<dim3(512), 256, 0, stream>>>(
      Afir, Zb, Yb, stats2, nullptr, 32768);
  bn_apply_relu8<<<dim3(1600), 256, 0, stream>>>(Yb, stats2, g2, b2);

  // layer 3: GEMM (12800 x 128 x 256), then FIR + fused softmax/time-sum
  gemm_rk64<256, 64, 2, 2, 5><<<dim3(100, 2), 256, 0, stream>>>(Yb, Wr3, Zb);
  fir_gemm64<32, false, true><<<dim3(64), 256, 0, stream>>>(
      Afir, Zb, nullptr, nullptr, out, 4096);
}

// Round 7
// 184.281 us; speedup vs baseline: 1.0490x; 1.0106x over previous
//
#include <hip/hip_runtime.h>
#include <stdint.h>

// ---------------------------------------------------------------------------
// d128snn_delays, round 17 = R16 (=R13 structure, best band 186.2-188.8us)
// + fir MFMA band-skip: Afir[t][k] is banded (s in [t-24,t]), so 45 of the
// 98 (a,k-subtile) MFMAs per wave multiply exact-zero A. Constexpr NEED
// table + full unroll -> guards constant-fold, zero runtime branches, zero
// memory-path changes. Bitwise-identical output (x+0=x); also makes the
// j=13 subtile (k>=416, poison rows) skipped for ALL a.
// Measured-dead-end ledger:
//   - inline BN in GEMM staging (R6): +VALU in K-loop critical path, net -.
//   - cooperative mega-kernel (R9): grid.sync() ~110us each on gfx950 -> 5x.
//   - XCD-aware swizzle (R10): serializes A-fill through one XCD's L2. -10us.
//   - R12 device-scope semaphore BN fusion: +55us PER SYNC. Never again.
//   - R14 gemm dbuf-B: half-pipeline (A still issued right before wait) ->
//     no latency hidden, LDS 48->80KB. Neutral-to-negative.
//   - R14/R15 fir poison-mask (conditional in prefetch-issue path): ~+5us
//     vs R13 band {186.2,188.8}. Conditional loads in the issue clause cost
//     more than L3-absorbed poison reads. MFMA-skip != load-skip.
// Same-code noise band: +-2.5us (R13=188.8, R16=186.2). Single-change
// accept threshold: >3us.
// Budget: ~42us harness fill + ~75us kernels + ~45us dispatch gaps.
// ---------------------------------------------------------------------------

#define T_LEN 100
#define B_SZ  128
#define M_ROWS 12800
#define R_RANK 4
#define K_FIR 448

typedef __bf16 v8bf __attribute__((ext_vector_type(8)));
typedef float  v4f  __attribute__((ext_vector_type(4)));
typedef unsigned int uint32;
typedef unsigned short ushort_t;

// PHI[tau][r] = exp(-u^2/2) * T_r(u), u = (tau-12)/12  (Chebyshev basis)
struct PhiT { float v[25][R_RANK]; };
constexpr double cexp_(double x) {
  double s = 1.0, t = 1.0;
  for (int n = 1; n < 30; ++n) { t = t * x / n; s += t; }
  return s;
}
constexpr PhiT make_phi() {
  PhiT P{};
  for (int tau = 0; tau < 25; ++tau) {
    double u = (tau - 12) / 12.0;
    double g = cexp_(-0.5 * u * u);
    double T0 = 1.0, T1 = u;
    P.v[tau][0] = (float)(g * T0);
    P.v[tau][1] = (float)(g * T1);
    for (int r = 2; r < R_RANK; ++r) {
      double T2 = 2.0 * u * T1 - T0;
      P.v[tau][r] = (float)(g * T2);
      T0 = T1; T1 = T2;
    }
  }
  return P;
}
constexpr PhiT PHI = make_phi();

// NEED[j][a]: does k-subtile j (k in [32j,32j+32)) intersect the Afir band
// of t-tile a (t in [16a,16a+16), band s in [t-24,t])? 53 of 98 true.
struct FirNeed { bool v[14][7]; };
constexpr FirNeed make_fir_need() {
  FirNeed f{};
  for (int j = 0; j < 14; ++j)
    for (int a = 0; a < 7; ++a) {
      bool need = false;
      for (int k = 32 * j; k < 32 * j + 32; ++k) {
        if (k >= 400) continue;           // rows 400+: Afir zero (and poison Z)
        int sd = k % 100;
        if (sd >= 16 * a - 24 && sd <= 16 * a + 15) need = true;
      }
      f.v[j][a] = need;
    }
  return f;
}
constexpr FirNeed FIRNEED = make_fir_need();

__device__ __forceinline__ void gl_lds16(const void* g, void* l) {
  __builtin_amdgcn_global_load_lds(
      (const __attribute__((address_space(1))) char*)g,
      (__attribute__((address_space(3))) char*)l, 16, 0, 0);
}

// ---------------------------------------------------------------------------
// Fused setup: 3x build_wr (Chebyshev/Bessel coeffs) + build_afir + fill_xb
// (vectorized: float4 loads, 8B bf16x4 stores) + stats zero.
// ---------------------------------------------------------------------------
__device__ __forceinline__ void build_wr_body(
    const float* __restrict__ W, const float* __restrict__ P,
    __bf16* __restrict__ Wr, int CIN, int CINP, int COUT, int COUTP, int o) {
  for (int i = threadIdx.x; i < CINP; i += blockDim.x) {
    bool valid = (o < COUT) && (i < CIN);
    float w = valid ? W[(size_t)o * CIN + i] : 0.f;
    float p = valid ? P[(size_t)o * CIN + i] : 0.f;
    float S = 0.f;
#pragma unroll
    for (int l = 0; l < 25; ++l) {
      float d = ((float)(l - 12) - p) * (1.f / 12.f);
      S += expf(-0.5f * d * d);
    }
    float v = p * (1.f / 12.f);
    float g = w * expf(-0.5f * v * v) / (S + 1e-7f);
    // modified Bessel I_r(v), r = 0..3, 7-term series (|v|<=1)
    float h = 0.5f * v, hh = h * h;
    float pw = 1.f;  // h^r / r!
#pragma unroll
    for (int r = 0; r < R_RANK; ++r) {
      float term = pw, sum = pw;
#pragma unroll
      for (int m = 1; m <= 6; ++m) {
        term *= hh / (float)(m * (m + r));
        sum += term;
      }
      float c = g * ((r == 0) ? 1.f : 2.f) * sum;
      Wr[((size_t)r * COUTP + o) * CINP + i] = (__bf16)c;
      pw *= h / (float)(r + 1);
    }
  }
}

__global__ void setup_all(const float* __restrict__ x,
                          const float* __restrict__ W1, const float* __restrict__ P1,
                          const float* __restrict__ W2, const float* __restrict__ P2,
                          const float* __restrict__ W3, const float* __restrict__ P3,
                          __bf16* __restrict__ Xb, __bf16* __restrict__ Wr1,
                          __bf16* __restrict__ Wr2, __bf16* __restrict__ Wr3,
                          __bf16* __restrict__ Af, float* __restrict__ stats) {
  int blk = blockIdx.x;
  if (blk < 256) { build_wr_body(W1, P1, Wr1, 700, 704, 256, 256, blk); return; }
  blk -= 256;
  if (blk < 256) { build_wr_body(W2, P2, Wr2, 256, 256, 256, 256, blk); return; }
  blk -= 256;
  if (blk < 32) { build_wr_body(W3, P3, Wr3, 256, 256, 20, 32, blk); return; }
  blk -= 32;
  if (blk < 196) {  // Afir (112 x 448): [t][r*100+s] = PHI[s-t+24][r], else 0
    int idx = blk * 256 + threadIdx.x;
    if (idx < 112 * 448) {
      int t = idx / 448, k = idx - t * 448;
      float v = 0.f;
      if (t < 100 && k < 400) {
        int r = k / 100, s = k - r * 100;
        int tau = s - t + 24;
        if (tau >= 0 && tau < 25) v = PHI.v[tau][r];
      }
      Af[idx] = (__bf16)v;
    }
    return;
  }
  blk -= 196;
  if (blk < 2200) {  // x (B,T,700) f32 -> Xb (T,B,704) bf16, vectorized.
    // chunk = 4 cols; 176 chunks/row (chunk 175 = pad), 12800 rows.
    // 2200 blocks * 256 thr * 4 chunks = 2,252,800 = 12800*176 exact cover.
    int c0 = blk * 1024 + threadIdx.x;
#pragma unroll
    for (int k = 0; k < 4; ++k) {
      int c = c0 + k * 256;
      int row = c / 176, col4 = c - row * 176;
      int t = row >> 7, b = row & 127;
      uint2 pk;
      __bf16* pb = (__bf16*)&pk;
      if (col4 < 175) {
        const float* src = x + ((size_t)b * T_LEN + t) * 700 + col4 * 4;
        float4 v = *(const float4*)src;   // 16B-aligned: row base 2800B, +16B
        pb[0] = (__bf16)v.x; pb[1] = (__bf16)v.y;
        pb[2] = (__bf16)v.z; pb[3] = (__bf16)v.w;
      } else {
        pk.x = 0u; pk.y = 0u;
      }
      *(uint2*)&Xb[(size_t)row * 704 + col4 * 4] = pk;
    }
    return;
  }
  blk -= 2200;
  if (blk == 0) {
    for (int i = threadIdx.x; i < 1024; i += 256) stats[i] = 0.f;
  }
}

// ---------------------------------------------------------------------------
// Main GEMM, BK=64: Z[k=(r,t)][n=(b,o)] = A @ Wr^T. Pure async-DMA staging.
// LDS: [row][64], 8-elem kgroup slot s holds logical group s^(row&7).
// ---------------------------------------------------------------------------
template <int CINP, int BLK_N, int WROWS, int WCOLS, int CO_SH>
__global__ __launch_bounds__(256, 2)
void gemm_rk64(const __bf16* __restrict__ A, const __bf16* __restrict__ Bm,
               __bf16* __restrict__ Z) {
  constexpr int COUTP = 1 << CO_SH;
  constexpr int WM = 128 / WROWS;
  constexpr int WN = BLK_N / WCOLS;
  constexpr int RM = WM / 16;
  constexpr int RN = WN / 16;
  __shared__ __align__(16) __bf16 sA[128 * 64];
  __shared__ __align__(16) __bf16 sB[BLK_N * 64];

  const int tid = threadIdx.x;
  const int w = tid >> 6, lane = tid & 63;
  const int q = lane >> 4, ln = lane & 15;
  const int wrow = w / WCOLS, wcol = w % WCOLS;
  const int srow8 = lane >> 3;
  const int s8 = lane & 7;

  const int t0 = blockIdx.x;
  const int oc = blockIdx.y * BLK_N;
  const __bf16* Abase = A + (size_t)t0 * 128 * CINP;
  const __bf16* Bbase = Bm + (size_t)oc * CINP;

  v4f acc[RM][RN];
#pragma unroll
  for (int a = 0; a < RM; ++a)
#pragma unroll
    for (int b = 0; b < RN; ++b) acc[a][b] = v4f{0.f, 0.f, 0.f, 0.f};

  for (int ic = 0; ic < CINP; ic += 64) {
    for (int j = w; j < 16; j += 4) {  // A: 128 rows, 8 rows/issue
      int m = j * 8 + srow8;
      int g = s8 ^ (m & 7);
      gl_lds16(Abase + (size_t)m * CINP + ic + g * 8, &sA[j * 512]);
    }
    for (int j = w; j < BLK_N / 8; j += 4) {  // B
      int n = j * 8 + srow8;
      int g = s8 ^ (n & 7);
      gl_lds16(Bbase + (size_t)n * CINP + ic + g * 8, &sB[j * 512]);
    }
    __syncthreads();

#pragma unroll
    for (int s = 0; s < 2; ++s) {
      v8bf af[RM], bfr[RN];
#pragma unroll
      for (int a = 0; a < RM; ++a) {
        int m = wrow * WM + a * 16 + ln;
        af[a] = *(const v8bf*)&sA[m * 64 + ((((s << 2) | q) ^ (m & 7)) * 8)];
      }
#pragma unroll
      for (int b = 0; b < RN; ++b) {
        int n = wcol * WN + b * 16 + ln;
        bfr[b] = *(const v8bf*)&sB[n * 64 + ((((s << 2) | q) ^ (n & 7)) * 8)];
      }
#pragma unroll
      for (int a = 0; a < RM; ++a)
#pragma unroll
        for (int b = 0; b < RN; ++b)
          acc[a][b] = __builtin_amdgcn_mfma_f32_16x16x32_bf16(af[a], bfr[b], acc[a][b], 0, 0, 0);
    }
    __syncthreads();
  }

  // C/D: col=lane&15, row=quad*4+reg (m89-verified)
#pragma unroll
  for (int a = 0; a < RM; ++a) {
#pragma unroll
    for (int b = 0; b < RN; ++b) {
      int n = oc + wcol * WN + b * 16 + ln;
      int r = n >> CO_SH, o = n & (COUTP - 1);
#pragma unroll
      for (int rr = 0; rr < 4; ++rr) {
        int m = t0 * 128 + wrow * WM + a * 16 + q * 4 + rr;
        Z[((size_t)r * M_ROWS + m) * COUTP + o] = (__bf16)acc[a][b][rr];
      }
    }
  }
}

// ---------------------------------------------------------------------------
// FIR GEMM, BK=64, K=448: Y(112 x 64-slice) = Afir(112x448) @ Z(448xN).
// B transposed in LDS (k-pair packed b32, [n][35-dword stride]).
// Double-buffered (2x23296B), counted-wait pipeline (R13). K-loop fully
// unrolled; MFMAs guarded by constexpr FIRNEED band table (53/98 issued,
// guards constant-fold). Staging untouched (load-skip measured -5us, R14/15).
// STATS: fused BN sum/sumsq atomics.  SOFTMAX (L3): in-LDS softmax + t-sum.
// ---------------------------------------------------------------------------
template <int COUTP, bool STATS, bool SOFTMAX>
__global__ __launch_bounds__(256, 2)
void fir_gemm64(const __bf16* __restrict__ Af, const __bf16* __restrict__ Z,
                __bf16* __restrict__ Yout, float* __restrict__ stats,
                float* __restrict__ outp, int N) {
  __shared__ __align__(16) unsigned char smem[46592];  // 2 x (14336 + 8960)

  const int tid = threadIdx.x;
  const int w = tid >> 6, lane = tid & 63;
  const int q = lane >> 4, ln = lane & 15;
  const int srow8 = lane >> 3, s8 = lane & 7;
  const int kp = tid >> 3;    // 0..31
  const int noct = tid & 7;   // 0..7
  const int nb = blockIdx.x * 64;

  v4f acc[7];
#pragma unroll
  for (int a = 0; a < 7; ++a) acc[a] = v4f{0.f, 0.f, 0.f, 0.f};

  uint4 r0, r1;  // B-regs for the tile about to be written to LDS

  // buffer b: sA = smem + b*23296 (14336 B), sBu = smem + b*23296 + 14336
#define SA_BUF(b) ((__bf16*)(smem + (b) * 23296))
#define SB_BUF(b) ((uint32*)(smem + (b) * 23296 + 14336))

  // ---- prologue: issue tile 0 ----
  {
    __bf16* sA = SA_BUF(0);
    for (int j = w; j < 14; j += 4) {
      int m = j * 8 + srow8;
      int g = s8 ^ (m & 7);
      gl_lds16(Af + (size_t)m * K_FIR + 0 + g * 8, &sA[j * 512]);
    }
    const __bf16* zp = Z + (size_t)(0 + kp * 2) * N + nb + noct * 8;
    r0 = *(const uint4*)zp;
    r1 = *(const uint4*)(zp + N);
  }

#pragma unroll
  for (int i = 0; i < 7; ++i) {
    const int cb = i & 1;
    // wait: tile i's A-DMA + B-regs (issued one compute-phase ago)
    asm volatile("s_waitcnt vmcnt(0)" ::: "memory");
    // write B(i) -> LDS (transposed, k-pair packed)
    {
      uint32* sBu = SB_BUF(cb);
      const ushort_t* p0 = (const ushort_t*)&r0;
      const ushort_t* p1 = (const ushort_t*)&r1;
#pragma unroll
      for (int j = 0; j < 8; ++j) {
        uint32 val = (uint32)p0[j] | ((uint32)p1[j] << 16);
        sBu[(noct * 8 + j) * 35 + kp] = val;
      }
    }
    // issue tile i+1 (in flight across compute(i))
    if (i < 6) {
      int kc = (i + 1) * 64;
      __bf16* sA = SA_BUF(cb ^ 1);
      for (int j = w; j < 14; j += 4) {
        int m = j * 8 + srow8;
        int g = s8 ^ (m & 7);
        gl_lds16(Af + (size_t)m * K_FIR + kc + g * 8, &sA[j * 512]);
      }
      const __bf16* zp = Z + (size_t)(kc + kp * 2) * N + nb + noct * 8;
      r0 = *(const uint4*)zp;
      r1 = *(const uint4*)(zp + N);
    }
    asm volatile("s_waitcnt lgkmcnt(0)" ::: "memory");  // our ds_writes done
    __builtin_amdgcn_s_barrier();                       // raw: no vmcnt drain

    {
      __bf16* sA = SA_BUF(cb);
      uint32* sBu = SB_BUF(cb);
#pragma unroll
      for (int s = 0; s < 2; ++s) {
        v8bf af[7];
#pragma unroll
        for (int a = 0; a < 7; ++a) {
          if (FIRNEED.v[2 * i + s][a]) {
            int m = a * 16 + ln;
            af[a] = *(const v8bf*)&sA[m * 64 + ((((s << 2) | q) ^ (m & 7)) * 8)];
          }
        }
        int base = (w * 16 + ln) * 35 + s * 16 + q * 4;
        uint32 tmp[4] = {sBu[base], sBu[base + 1], sBu[base + 2], sBu[base + 3]};
        v8bf bfr = *(const v8bf*)tmp;
#pragma unroll
        for (int a = 0; a < 7; ++a) {
          if (FIRNEED.v[2 * i + s][a])
            acc[a] = __builtin_amdgcn_mfma_f32_16x16x32_bf16(af[a], bfr, acc[a], 0, 0, 0);
        }
      }
    }
    __builtin_amdgcn_s_barrier();  // all waves done reading before buf reuse
  }

  int ng = nb + w * 16 + ln;
  if (!SOFTMAX) {
    float s = 0.f, ss = 0.f;
#pragma unroll
    for (int a = 0; a < 7; ++a) {
#pragma unroll
      for (int rr = 0; rr < 4; ++rr) {
        int t = a * 16 + q * 4 + rr;
        float v = acc[a][rr];
        if (t < 100) {
          Yout[(size_t)t * N + ng] = (__bf16)v;
          s += v; ss += v * v;
        }
      }
    }
    if (STATS) {
      s += __shfl_xor(s, 16); ss += __shfl_xor(ss, 16);
      s += __shfl_xor(s, 32); ss += __shfl_xor(ss, 32);
      if (q == 0) {
        int o = ng & (COUTP - 1);
        atomicAdd(&stats[o], s);
        atomicAdd(&stats[COUTP + o], ss);
      }
    }
  } else {
    // L3: this block holds all t and all o for 2 batch entries.
    float* smx = (float*)smem;               // [100][65] = 26000 B (reuses bufs)
    float* lacc = (float*)(smem + 26000);    // 40 floats
    int col = w * 16 + ln;
#pragma unroll
    for (int a = 0; a < 7; ++a) {
#pragma unroll
      for (int rr = 0; rr < 4; ++rr) {
        int t = a * 16 + q * 4 + rr;
        if (t < 100) smx[t * 65 + col] = acc[a][rr];
      }
    }
    if (tid < 64) lacc[tid & 63] = 0.f;
    __syncthreads();
    if (tid < 200) {
      int bl = tid / 100, t = tid - bl * 100;
      const float* rr = &smx[t * 65 + bl * 32];
      float v[20], m = -1e30f;
#pragma unroll
      for (int o = 0; o < 20; ++o) { v[o] = rr[o]; m = fmaxf(m, v[o]); }
      float sum = 0.f;
#pragma unroll
      for (int o = 0; o < 20; ++o) { v[o] = expf(v[o] - m); sum += v[o]; }
      float inv = 1.f / sum;
#pragma unroll
      for (int o = 0; o < 20; ++o) atomicAdd(&lacc[bl * 20 + o], v[o] * inv);
    }
    __syncthreads();
    if (tid < 40) {
      int bl = tid / 20, o = tid - bl * 20;
      int b = (nb >> 5) + bl;
      outp[b * 20 + o] = lacc[bl * 20 + o];
    }
  }
#undef SA_BUF
#undef SB_BUF
}

// normalize + relu, bf16x8 vectorized, in-place on Y
__global__ __launch_bounds__(256)
void bn_apply_relu8(__bf16* __restrict__ h, const float* __restrict__ stats,
                    const float* __restrict__ gamma, const float* __restrict__ beta) {
  int idx = blockIdx.x * 256 + threadIdx.x;
  int co = (idx & 31) * 8;
  size_t row = (size_t)(idx >> 5);
  __bf16* p = h + row * 256 + co;
  uint4 raw = *(const uint4*)p;
  const ushort_t* pr = (const ushort_t*)&raw;
  uint4 outv;
  ushort_t* po = (ushort_t*)&outv;
#pragma unroll
  for (int j = 0; j < 8; ++j) {
    int c = co + j;
    float mean = stats[c] * (1.f / 12800.f);
    float var = stats[256 + c] * (1.f / 12800.f) - mean * mean;
    float inv = rsqrtf(var + 1e-5f) * gamma[c];
    uint32 u = (uint32)pr[j] << 16;
    float xv; __builtin_memcpy(&xv, &u, 4);
    float v = (xv - mean) * inv + beta[c];
    v = fmaxf(v, 0.f);
    __bf16 bv = (__bf16)v;
    po[j] = *(const ushort_t*)&bv;
  }
  *(uint4*)p = outv;
}

// ---------------------------------------------------------------------------

extern "C" void kernel_launch(void* const* d_in, const int* in_sizes, int n_in,
                              void* d_out, int out_size, void* d_ws, size_t ws_size,
                              hipStream_t stream) {
  const float* x  = (const float*)d_in[0];
  const float* W1 = (const float*)d_in[1];
  const float* P1 = (const float*)d_in[2];
  const float* W2 = (const float*)d_in[3];
  const float* P2 = (const float*)d_in[4];
  const float* W3 = (const float*)d_in[5];
  const float* P3 = (const float*)d_in[6];
  const float* g1 = (const float*)d_in[7];
  const float* b1 = (const float*)d_in[8];
  const float* g2 = (const float*)d_in[9];
  const float* b2 = (const float*)d_in[10];
  float* out = (float*)d_out;

  constexpr size_t XB_B  = (size_t)M_ROWS * 704 * 2;        // 18,022,400
  constexpr size_t Z_B   = (size_t)K_FIR * 32768 * 2;       // 29,360,128
  constexpr size_t Y12_B = (size_t)M_ROWS * 256 * 2;        //  6,553,600
  constexpr size_t W1_B  = (size_t)R_RANK * 256 * 704 * 2;  //  1,441,792
  constexpr size_t W2_B  = (size_t)R_RANK * 256 * 256 * 2;  //    524,288
  constexpr size_t W3_B  = (size_t)R_RANK * 32 * 256 * 2;   //     65,536
  constexpr size_t AF_B  = (size_t)112 * K_FIR * 2;         //    100,352
  constexpr size_t ST_B  = 4096;
  constexpr size_t TOTAL = XB_B + Z_B + Y12_B + W1_B + W2_B + W3_B + AF_B + ST_B;
  if (ws_size < TOTAL) return;

  char* ws = (char*)d_ws;
  size_t off = 0;
  __bf16* Xb   = (__bf16*)(ws + off); off += XB_B;
  __bf16* Zb   = (__bf16*)(ws + off); off += Z_B;
  __bf16* Yb   = (__bf16*)(ws + off); off += Y12_B;   // Y1 then Y2 (in-place BN)
  __bf16* Wr1  = (__bf16*)(ws + off); off += W1_B;
  __bf16* Wr2  = (__bf16*)(ws + off); off += W2_B;
  __bf16* Wr3  = (__bf16*)(ws + off); off += W3_B;
  __bf16* Afir = (__bf16*)(ws + off); off += AF_B;
  float*  stats1 = (float*)(ws + off);
  float*  stats2 = stats1 + 512;

  // fused setup: 256+256+32+196+2200+1 blocks
  setup_all<<<dim3(2941), 256, 0, stream>>>(x, W1, P1, W2, P2, W3, P3,
                                            Xb, Wr1, Wr2, Wr3, Afir, stats1);

  // layer 1: GEMM (12800 x 1024 x 704), BLK_N=256 -> FIR (+stats) -> BN in-place
  gemm_rk64<704, 256, 2, 2, 8><<<dim3(100, 4), 256, 0, stream>>>(Xb, Wr1, Zb);
  fir_gemm64<256, true, false><<<dim3(512), 256, 0, stream>>>(
      Afir, Zb, Yb, stats1, nullptr, 32768);
  bn_apply_relu8<<<dim3(1600), 256, 0, stream>>>(Yb, stats1, g1, b1);

  // layer 2: GEMM (12800 x 1024 x 256), BLK_N=256
  gemm_rk64<256, 256, 2, 2, 8><<<dim3(100, 4), 256, 0, stream>>>(Yb, Wr2, Zb);
  fir_gemm64<256, true, false><<<dim3(512), 256, 0, stream>>>(
      Afir, Zb, Yb, stats2, nullptr, 32768);
  bn_apply_relu8<<<dim3(1600), 256, 0, stream>>>(Yb, stats2, g2, b2);

  // layer 3: GEMM (12800 x 128 x 256), then FIR + fused softmax/time-sum
  gemm_rk64<256, 64, 2, 2, 5><<<dim3(100, 2), 256, 0, stream>>>(Yb, Wr3, Zb);
  fir_gemm64<32, false, true><<<dim3(64), 256, 0, stream>>>(
      Afir, Zb, nullptr, nullptr, out, 4096);
}